// Round 2
// baseline (1402.903 us; speedup 1.0000x reference)
//
#include <hip/hip_runtime.h>
#include <hip/hip_bf16.h>
#include <stdint.h>
#include <stddef.h>

#define NSP 110592      // 48^3
#define SD  48
#define SD2 2304        // 48*48
#define CIN 128
#define C3  384
#define NH  8
#define NB  2
#define NQ  84934656ull // NB*C3*NSP

typedef __hip_bfloat16 bf16;
typedef __bf16 bf16x8 __attribute__((ext_vector_type(8)));
typedef float  f32x4  __attribute__((ext_vector_type(4)));

// wbuf element offsets (all bf16): qkvw | dww | projw | temp
#define WOFF_QKVW 0
#define WOFF_DWW  49152
#define WOFF_PROJ 59520
#define WOFF_TEMP 75904
#define WTOTAL    75912

__device__ __forceinline__ float ldb(const bf16* p){ return __bfloat162float(*p); }
__device__ __forceinline__ float b2f(uint16_t u){
    union { float f; uint32_t i; } x; x.i = (uint32_t)u << 16; return x.f;
}
__device__ __forceinline__ uint16_t f2b(float f){
    bf16 h = __float2bfloat16(f); return *(uint16_t*)&h;
}
// async 16B global -> LDS (DMA, no VGPR roundtrip); dest = wave base + lane*16
__device__ __forceinline__ void gload_lds16(const void* g, void* l){
    __builtin_amdgcn_global_load_lds(
        (const __attribute__((address_space(1))) void*)g,
        (__attribute__((address_space(3))) void*)l, 16, 0, 0);
}

// ---- sniffer: flag=1 if inputs are fp32, 0 if bf16 ---------------------------
__global__ void k_sniff(const uint16_t* __restrict__ x16, int* __restrict__ flag)
{
    int t = threadIdx.x; int cnt = 0;
    for (int i = 0; i < 16; ++i) {
        uint16_t b = x16[(size_t)(t * 16 + i) * 2];   // even halves only
        int e = (b >> 7) & 0xFF;
        if (e >= 100 && e <= 140) ++cnt;              // bf16-exponent-plausible
    }
    for (int off = 32; off; off >>= 1) cnt += __shfl_down(cnt, off, 64);
    __shared__ int s[4];
    if ((t & 63) == 0) s[t >> 6] = cnt;
    __syncthreads();
    if (t == 0) *flag = (s[0] + s[1] + s[2] + s[3] < 2048) ? 1 : 0;
}

// ---- canonicalize all weights to bf16 in wbuf --------------------------------
__global__ void k_cvtw(const void* __restrict__ qw, const void* __restrict__ dw,
                       const void* __restrict__ pw, const void* __restrict__ tw,
                       bf16* __restrict__ wbuf, const int* __restrict__ flagp)
{
    int f = *flagp;
    int idx = blockIdx.x * 256 + threadIdx.x;
    if (idx >= WTOTAL) return;
    const void* src; int off;
    if (idx < WOFF_DWW)      { src = qw; off = idx; }
    else if (idx < WOFF_PROJ){ src = dw; off = idx - WOFF_DWW; }
    else if (idx < WOFF_TEMP){ src = pw; off = idx - WOFF_PROJ; }
    else                     { src = tw; off = idx - WOFF_TEMP; }
    float v = f ? ((const float*)src)[off]
                : __bfloat162float(((const bf16*)src)[off]);
    wbuf[idx] = __float2bfloat16(v);
}

// ---- K0: transpose x[b][c][n] -> xT[b][n][c] (bf16 out, dual-dtype in) -------
__global__ __launch_bounds__(256) void k_transpose(const void* __restrict__ xin,
                                                   bf16* __restrict__ xT,
                                                   const int* __restrict__ flagp)
{
    int f = *flagp;
    int b = blockIdx.y;
    size_t tid = (size_t)blockIdx.x * 256 + threadIdx.x;
    int c = (int)(tid & 127);
    size_t n8 = tid >> 7;
    size_t base = ((size_t)b * CIN + c) * NSP + n8 * 8;
    bf16 pv[8];
    if (f) {
        const float* src = (const float*)xin + base;
        float4 a = *(const float4*)src;
        float4 d = *(const float4*)(src + 4);
        pv[0] = __float2bfloat16(a.x); pv[1] = __float2bfloat16(a.y);
        pv[2] = __float2bfloat16(a.z); pv[3] = __float2bfloat16(a.w);
        pv[4] = __float2bfloat16(d.x); pv[5] = __float2bfloat16(d.y);
        pv[6] = __float2bfloat16(d.z); pv[7] = __float2bfloat16(d.w);
    } else {
        uint4 v = *(const uint4*)((const bf16*)xin + base);
        const bf16* q = (const bf16*)&v;
#pragma unroll
        for (int j = 0; j < 8; ++j) pv[j] = q[j];
    }
    bf16* dst = xT + ((size_t)b * NSP + n8 * 8) * CIN + c;
#pragma unroll
    for (int j = 0; j < 8; ++j) dst[(size_t)j * CIN] = pv[j];
}

// ---- GEMM  C[b][m][n] = A[m][k] * BT[b][n][k], K=128, 128x128 tiles ----------
__global__ __launch_bounds__(256) void k_gemm_bt(const bf16* __restrict__ A,
                                                 const bf16* __restrict__ BT,
                                                 void* __restrict__ Cout,
                                                 int Mtotal,
                                                 const int* __restrict__ flagp,
                                                 int mblocks)
{
    __shared__ __align__(16) bf16 lA[128 * CIN];
    __shared__ __align__(16) bf16 lB[128 * CIN];
    int b = blockIdx.z;
    int bx = blockIdx.x;
    int mb, nb;
    if (mblocks == 3) {
        int g = bx / 24, w = bx % 24;
        nb = g * 8 + (w & 7);
        mb = w >> 3;
    } else { mb = 0; nb = bx; }
    size_t nbase = (size_t)nb * 128;
    const bf16* gA = A + (size_t)mb * 128 * CIN;
    const bf16* gB = BT + ((size_t)b * NSP + nbase) * CIN;
    int t = threadIdx.x;
#pragma unroll
    for (int i = 0; i < 8; ++i) {
        int off = (i * 256 + t) * 8;
        *(uint4*)&lA[off] = *(const uint4*)&gA[off];
        *(uint4*)&lB[off] = *(const uint4*)&gB[off];
    }
    __syncthreads();

    int wave = t >> 6, lane = t & 63;
    int wm = (wave & 1) * 64, wn = (wave >> 1) * 64;
    int lr = lane & 15, lq = lane >> 4;
    f32x4 acc[4][4];
#pragma unroll
    for (int mi = 0; mi < 4; ++mi)
#pragma unroll
        for (int ni = 0; ni < 4; ++ni) acc[mi][ni] = (f32x4){0.f, 0.f, 0.f, 0.f};

#pragma unroll
    for (int ks = 0; ks < 4; ++ks) {
        int kof = ks * 32 + lq * 8;
        bf16x8 af[4], bfv[4];
#pragma unroll
        for (int mi = 0; mi < 4; ++mi)
            af[mi] = *(const bf16x8*)&lA[(wm + mi * 16 + lr) * CIN + kof];
#pragma unroll
        for (int ni = 0; ni < 4; ++ni)
            bfv[ni] = *(const bf16x8*)&lB[(wn + ni * 16 + lr) * CIN + kof];
#pragma unroll
        for (int mi = 0; mi < 4; ++mi)
#pragma unroll
            for (int ni = 0; ni < 4; ++ni)
                acc[mi][ni] = __builtin_amdgcn_mfma_f32_16x16x32_bf16(
                    af[mi], bfv[ni], acc[mi][ni], 0, 0, 0);
    }

    int f32o = flagp ? *flagp : 0;
    size_t cb = ((size_t)b * Mtotal + (size_t)mb * 128) * NSP + nbase;
    if (f32o) {
        float* Cb = (float*)Cout + cb;
#pragma unroll
        for (int mi = 0; mi < 4; ++mi)
#pragma unroll
            for (int ni = 0; ni < 4; ++ni)
#pragma unroll
                for (int r = 0; r < 4; ++r)
                    Cb[(size_t)(wm + mi * 16 + lq * 4 + r) * NSP + wn + ni * 16 + lr]
                        = acc[mi][ni][r];
    } else {
        bf16* Cb = (bf16*)Cout + cb;
#pragma unroll
        for (int mi = 0; mi < 4; ++mi)
#pragma unroll
            for (int ni = 0; ni < 4; ++ni)
#pragma unroll
                for (int r = 0; r < 4; ++r)
                    Cb[(size_t)(wm + mi * 16 + lq * 4 + r) * NSP + wn + ni * 16 + lr]
                        = __float2bfloat16(acc[mi][ni][r]);
    }
}

// ---- K2: depthwise 3x3x3 conv ------------------------------------------------
// Round-0 compute structure (6-z slabs, 4-wide strips, scalar FMA) with:
//  * 96B LDS rows (no d-halo cols) -> LDS 38.4KB -> 4 blocks/CU (was 3)
//  * plane interiors contiguous -> staging via global_load_lds DMA (no VGPR
//    roundtrip, no ds_writes)
//  * zero phase only for y-halo rows + pads + z-edge planes (~1.7KB, was 51KB)
//  * d-edge columns handled by cndmask (c4==0 / c4==44)
// Plane layout (elements): 8 head pad | 8 planes x (50 rows x 48) | 8 tail pad.
#define PLE 2400        // 50*48 elements per plane
__global__ __launch_bounds__(256, 4) void k_dwconv(const bf16* __restrict__ qkv1,
                                                   const bf16* __restrict__ dw,
                                                   bf16* __restrict__ qkv2,
                                                   float* __restrict__ sums)
{
    __shared__ __align__(16) bf16 lds[16 + 8 * PLE];   // 38432 B
    __shared__ float red[4];
    int bc = blockIdx.x;
    int slab = blockIdx.y;
    int z0 = slab * 6;
    int ch = bc % C3;
    int t = threadIdx.x;
    const bf16* src = qkv1 + (size_t)bc * NSP;
    bf16* dst = qkv2 + (size_t)bc * NSP;

    float wgt[27];
#pragma unroll
    for (int i = 0; i < 27; ++i) wgt[i] = ldb(&dw[ch * 27 + i]);

    // phase 0a: zero pads + y-halo rows (98 x uint4)
    if (t < 98) {
        int e;
        if (t == 0)       e = 0;                 // head pad
        else if (t == 97) e = 8 + 8 * PLE;       // tail pad
        else {
            int j = t - 1;                        // 0..95
            int p = j / 12, r12 = j - p * 12;
            int rr = r12 / 6, q = r12 - rr * 6;   // rr: 0=row0, 1=row49
            e = 8 + p * PLE + rr * 2352 + q * 8;  // 49*48 = 2352
        }
        *(uint4*)&lds[e] = (uint4){0, 0, 0, 0};
    }
    // phase 0b: zero z-edge plane (only slabs 0 and 7)
    if (slab == 0 || slab == 7) {
        int p = (slab == 0) ? 0 : 7;
        bf16* pb = lds + 8 + p * PLE;
        for (int k = t; k < 300; k += 256)
            *(uint4*)&pb[k * 8] = (uint4){0, 0, 0, 0};
    }

    // phase 1: DMA-stage 8 plane interiors (rows 1..48 = 4608B contiguous).
    // 40 chunk-slots: plane p chunk c (c<4: 1024B full-wave, c==4: 512B half).
    {
        int w = t >> 6, lane = t & 63;
#pragma unroll
        for (int i = 0; i < 10; ++i) {
            int g = w + i * 4;                    // 0..39, unique per slot
            int p = g / 5, c = g - p * 5;
            int zp = z0 - 1 + p;
            if ((unsigned)zp < SD) {
                const bf16* ga = src + (size_t)zp * SD2 + c * 512 + lane * 8;
                bf16* la = lds + 8 + p * PLE + 48 + c * 512 + lane * 8;
                if (c < 4)              gload_lds16(ga, la);
                else if (lane < 32)     gload_lds16(ga, la);
            }
        }
    }
    __syncthreads();   // drains vmcnt(0) + lgkm before compute

    // phase 2: 576 strips: s -> y = s/12, d-base c4 = (s%12)*4
    float ssq = 0.f;
#pragma unroll 1
    for (int r = 0; r < 3; ++r) {
        int s = r * 256 + t;
        if (s < 576) {
            int y = s / 12;
            int c4 = (s - y * 12) * 4;
            float acc[6][4];
#pragma unroll
            for (int oz = 0; oz < 6; ++oz)
#pragma unroll
                for (int d = 0; d < 4; ++d) acc[oz][d] = 0.f;

#pragma unroll
            for (int pl = 0; pl < 8; ++pl) {
                const uint16_t* P =
                    (const uint16_t*)lds + 8 + pl * PLE + y * 48 + c4;
                float v[3][6];
#pragma unroll
                for (int dy = 0; dy < 3; ++dy) {
                    const uint16_t* R = P + dy * 48;
                    uint2 m = *(const uint2*)R;            // cols c4..c4+3 (8B aligned)
                    v[dy][0] = (c4 == 0)  ? 0.f : b2f(R[-1]);
                    v[dy][1] = b2f((uint16_t)m.x);
                    v[dy][2] = b2f((uint16_t)(m.x >> 16));
                    v[dy][3] = b2f((uint16_t)m.y);
                    v[dy][4] = b2f((uint16_t)(m.y >> 16));
                    v[dy][5] = (c4 == 44) ? 0.f : b2f(R[4]);
                }
                float p0[4] = {0.f,0.f,0.f,0.f};
                float p1[4] = {0.f,0.f,0.f,0.f};
                float p2[4] = {0.f,0.f,0.f,0.f};
#pragma unroll
                for (int dy = 0; dy < 3; ++dy)
#pragma unroll
                    for (int dd = 0; dd < 3; ++dd) {
                        float w0 = wgt[dy * 3 + dd];
                        float w1 = wgt[9 + dy * 3 + dd];
                        float w2 = wgt[18 + dy * 3 + dd];
#pragma unroll
                        for (int d = 0; d < 4; ++d) {
                            float xv = v[dy][d + dd];
                            if (pl <= 5)            p0[d] += w0 * xv;
                            if (pl >= 1 && pl <= 6) p1[d] += w1 * xv;
                            if (pl >= 2)            p2[d] += w2 * xv;
                        }
                    }
#pragma unroll
                for (int d = 0; d < 4; ++d) {
                    if (pl <= 5)            acc[pl][d]     += p0[d];
                    if (pl >= 1 && pl <= 6) acc[pl - 1][d] += p1[d];
                    if (pl >= 2)            acc[pl - 2][d] += p2[d];
                }
            }
#pragma unroll
            for (int oz = 0; oz < 6; ++oz) {
                uint16_t u0 = f2b(acc[oz][0]), u1 = f2b(acc[oz][1]);
                uint16_t u2 = f2b(acc[oz][2]), u3 = f2b(acc[oz][3]);
                uint2 o;
                o.x = (uint32_t)u0 | ((uint32_t)u1 << 16);
                o.y = (uint32_t)u2 | ((uint32_t)u3 << 16);
                *(uint2*)&dst[(size_t)(z0 + oz) * SD2 + y * SD + c4] = o;
#pragma unroll
                for (int d = 0; d < 4; ++d) ssq += acc[oz][d] * acc[oz][d];
            }
        }
    }

    for (int off = 32; off; off >>= 1) ssq += __shfl_down(ssq, off, 64);
    if ((t & 63) == 0) red[t >> 6] = ssq;
    __syncthreads();
    if (t == 0) atomicAdd(&sums[bc], red[0] + red[1] + red[2] + red[3]);
}

// ---- K3: scores S[b][h][i][j] = sum_n q_i k_j  (MFMA, full n coverage) -------
__global__ __launch_bounds__(256) void k_scores(const bf16* __restrict__ qkv2,
                                                float* __restrict__ scores)
{
    int b = blockIdx.z, h = blockIdx.y;
    const bf16* qb = qkv2 + ((size_t)b * C3 + h * 16) * NSP;
    const bf16* kb = qkv2 + ((size_t)b * C3 + 128 + h * 16) * NSP;
    int t = threadIdx.x, w = t >> 6, lane = t & 63;
    int m = lane & 15, q4 = lane >> 4;
    size_t n0 = (size_t)blockIdx.x * 1024 + (size_t)w * 256 + (size_t)q4 * 8;
    const bf16* qp = qb + (size_t)m * NSP + n0;
    const bf16* kp = kb + (size_t)m * NSP + n0;
    f32x4 acc = (f32x4){0.f, 0.f, 0.f, 0.f};
#pragma unroll
    for (int it = 0; it < 8; ++it) {
        bf16x8 a  = *(const bf16x8*)(qp + it * 32);
        bf16x8 bb = *(const bf16x8*)(kp + it * 32);
        acc = __builtin_amdgcn_mfma_f32_16x16x32_bf16(a, bb, acc, 0, 0, 0);
    }
    float* srow = scores + (size_t)(b * NH + h) * 256;
#pragma unroll
    for (int r = 0; r < 4; ++r)
        atomicAdd(&srow[(q4 * 4 + r) * 16 + m], acc[r]);
}

// ---- K4: normalize + temperature + softmax -----------------------------------
__global__ void k_softmax(const float* __restrict__ scores,
                          const float* __restrict__ sums,
                          const bf16* __restrict__ temp,
                          float* __restrict__ attn)
{
    int t = threadIdx.x;             // t = b*128 + h*16 + i
    int h = (t >> 4) & 7, b = t >> 7;
    float tau = __bfloat162float(temp[h]);
    float invq = 1.f / fmaxf(sqrtf(sums[b * C3 + (t & 127)]), 1e-12f);
    const float* srow = scores + (size_t)t * 16;
    float s[16]; float mx = -3.4e38f;
#pragma unroll
    for (int j = 0; j < 16; ++j) {
        float invk = 1.f / fmaxf(sqrtf(sums[b * C3 + 128 + h * 16 + j]), 1e-12f);
        s[j] = srow[j] * invq * invk * tau;
        mx = fmaxf(mx, s[j]);
    }
    float sum = 0.f;
#pragma unroll
    for (int j = 0; j < 16; ++j) { s[j] = expf(s[j] - mx); sum += s[j]; }
    float inv = 1.f / sum;
    float* arow = attn + (size_t)t * 16;
#pragma unroll
    for (int j = 0; j < 16; ++j) arow[j] = s[j] * inv;
}

// ---- K5: outT[b][n][h*16+i] = sum_j attn[i][j] v[j][n] -----------------------
__global__ __launch_bounds__(256) void k_av(const bf16* __restrict__ qkv2,
                                            const float* __restrict__ attn,
                                            bf16* __restrict__ outT)
{
    int b = blockIdx.z, h = blockIdx.y;
    const bf16* vb = qkv2 + ((size_t)b * C3 + 256 + h * 16) * NSP;
    __shared__ float at[256];        // at[j*16+i]
    int t = threadIdx.x;
    {
        int i = t >> 4, j = t & 15;
        at[j * 16 + i] = attn[(size_t)(b * NH + h) * 256 + t];
    }
    __syncthreads();
    size_t n0 = (size_t)blockIdx.x * 1024 + (size_t)t * 4;
    float acc[16][4];
#pragma unroll
    for (int i = 0; i < 16; ++i)
#pragma unroll
        for (int k = 0; k < 4; ++k) acc[i][k] = 0.f;
#pragma unroll
    for (int j = 0; j < 16; ++j) {
        uint2 raw = *(const uint2*)&vb[(size_t)j * NSP + n0];
        const bf16* rp = (const bf16*)&raw;
        float vf[4];
#pragma unroll
        for (int k = 0; k < 4; ++k) vf[k] = ldb(&rp[k]);
#pragma unroll
        for (int i = 0; i < 16; ++i) {
            float wv = at[j * 16 + i];
#pragma unroll
            for (int k = 0; k < 4; ++k) acc[i][k] += wv * vf[k];
        }
    }
    bf16* ob = outT + ((size_t)b * NSP + n0) * CIN + h * 16;
#pragma unroll
    for (int k = 0; k < 4; ++k) {
        bf16 tmp[16];
#pragma unroll
        for (int i = 0; i < 16; ++i) tmp[i] = __float2bfloat16(acc[i][k]);
        *(uint4*)&ob[(size_t)k * CIN]     = *(uint4*)&tmp[0];
        *(uint4*)&ob[(size_t)k * CIN + 8] = *(uint4*)&tmp[8];
    }
}

// ---- host --------------------------------------------------------------------
extern "C" void kernel_launch(void* const* d_in, const int* in_sizes, int n_in,
                              void* d_out, int out_size, void* d_ws, size_t ws_size,
                              hipStream_t stream)
{
    const void *px = nullptr, *pq = nullptr, *pd = nullptr, *pp = nullptr, *pt = nullptr;
    for (int i = 0; i < n_in; ++i) {
        switch (in_sizes[i]) {
            case 28311552: px = d_in[i]; break;   // x
            case 49152:    pq = d_in[i]; break;   // qkv_w
            case 10368:    pd = d_in[i]; break;   // dw_w
            case 16384:    pp = d_in[i]; break;   // proj_w
            case 8:        pt = d_in[i]; break;   // temperature
        }
    }
    const size_t required = NQ * 4 + (1u << 20);
    if (!px || !pq || !pd || !pp || !pt || ws_size < required) {
        (void)hipMemsetAsync(d_out, 0, (size_t)out_size * 2, stream);
        return;
    }

    char* ws = (char*)d_ws;
    bf16* qkv1 = (bf16*)ws;                       // NQ bf16
    bf16* qkv2 = (bf16*)(ws + NQ * 2);            // NQ bf16
    char* small = ws + NQ * 4;
    int*   flag   = (int*)small;
    float* sums   = (float*)(small + 256);
    float* scores = (float*)(small + 8192);
    float* attn   = (float*)(small + 24576);
    bf16*  wbuf   = (bf16*)(small + 40960);
    bf16* xT   = qkv2;   // alias: dead before k_dwconv writes qkv2
    bf16* outT = qkv1;   // alias: qkv1 dead after k_dwconv

    (void)hipMemsetAsync(small, 0, 40960, stream);  // flag, sums, scores, attn
    k_sniff<<<1, 256, 0, stream>>>((const uint16_t*)px, flag);
    k_cvtw<<<(WTOTAL + 255) / 256, 256, 0, stream>>>(pq, pd, pp, pt, wbuf, flag);
    k_transpose<<<dim3(6912, NB), 256, 0, stream>>>(px, xT, flag);
    k_gemm_bt<<<dim3(864 * 3, 1, NB), 256, 0, stream>>>(
        wbuf + WOFF_QKVW, xT, qkv1, C3, nullptr, 3);
    k_dwconv<<<dim3(NB * C3, 8), 256, 0, stream>>>(qkv1, wbuf + WOFF_DWW, qkv2, sums);
    k_scores<<<dim3(108, NH, NB), 256, 0, stream>>>(qkv2, scores);
    k_softmax<<<1, 256, 0, stream>>>(scores, sums, wbuf + WOFF_TEMP, attn);
    k_av<<<dim3(108, NH, NB), 256, 0, stream>>>(qkv2, attn, outT);
    k_gemm_bt<<<dim3(864, 1, NB), 256, 0, stream>>>(
        wbuf + WOFF_PROJ, outT, d_out, CIN, flag, 1);
}

// Round 3
// 1320.637 us; speedup vs baseline: 1.0623x; 1.0623x over previous
//
#include <hip/hip_runtime.h>
#include <hip/hip_bf16.h>
#include <stdint.h>
#include <stddef.h>

#define NSP 110592      // 48^3
#define SD  48
#define SD2 2304        // 48*48
#define CIN 128
#define C3  384
#define NH  8
#define NB  2
#define NQ  84934656ull // NB*C3*NSP

typedef __hip_bfloat16 bf16;
typedef __bf16 bf16x8 __attribute__((ext_vector_type(8)));
typedef float  f32x4  __attribute__((ext_vector_type(4)));

// wbuf element offsets (all bf16): qkvw | dww | projw | temp
#define WOFF_QKVW 0
#define WOFF_DWW  49152
#define WOFF_PROJ 59520
#define WOFF_TEMP 75904
#define WTOTAL    75912

__device__ __forceinline__ float ldb(const bf16* p){ return __bfloat162float(*p); }
__device__ __forceinline__ float b2f(uint16_t u){
    union { float f; uint32_t i; } x; x.i = (uint32_t)u << 16; return x.f;
}
__device__ __forceinline__ uint16_t f2b(float f){
    bf16 h = __float2bfloat16(f); return *(uint16_t*)&h;
}

// ---- sniffer: flag=1 if inputs are fp32, 0 if bf16 ---------------------------
__global__ void k_sniff(const uint16_t* __restrict__ x16, int* __restrict__ flag)
{
    int t = threadIdx.x; int cnt = 0;
    for (int i = 0; i < 16; ++i) {
        uint16_t b = x16[(size_t)(t * 16 + i) * 2];   // even halves only
        int e = (b >> 7) & 0xFF;
        if (e >= 100 && e <= 140) ++cnt;              // bf16-exponent-plausible
    }
    for (int off = 32; off; off >>= 1) cnt += __shfl_down(cnt, off, 64);
    __shared__ int s[4];
    if ((t & 63) == 0) s[t >> 6] = cnt;
    __syncthreads();
    if (t == 0) *flag = (s[0] + s[1] + s[2] + s[3] < 2048) ? 1 : 0;
}

// ---- canonicalize all weights to bf16 in wbuf --------------------------------
__global__ void k_cvtw(const void* __restrict__ qw, const void* __restrict__ dw,
                       const void* __restrict__ pw, const void* __restrict__ tw,
                       bf16* __restrict__ wbuf, const int* __restrict__ flagp)
{
    int f = *flagp;
    int idx = blockIdx.x * 256 + threadIdx.x;
    if (idx >= WTOTAL) return;
    const void* src; int off;
    if (idx < WOFF_DWW)      { src = qw; off = idx; }
    else if (idx < WOFF_PROJ){ src = dw; off = idx - WOFF_DWW; }
    else if (idx < WOFF_TEMP){ src = pw; off = idx - WOFF_PROJ; }
    else                     { src = tw; off = idx - WOFF_TEMP; }
    float v = f ? ((const float*)src)[off]
                : __bfloat162float(((const bf16*)src)[off]);
    wbuf[idx] = __float2bfloat16(v);
}

// ---- K0: transpose x[b][c][n] -> xT[b][n][c] (bf16 out, dual-dtype in) -------
__global__ __launch_bounds__(256) void k_transpose(const void* __restrict__ xin,
                                                   bf16* __restrict__ xT,
                                                   const int* __restrict__ flagp)
{
    int f = *flagp;
    int b = blockIdx.y;
    size_t tid = (size_t)blockIdx.x * 256 + threadIdx.x;
    int c = (int)(tid & 127);
    size_t n8 = tid >> 7;
    size_t base = ((size_t)b * CIN + c) * NSP + n8 * 8;
    bf16 pv[8];
    if (f) {
        const float* src = (const float*)xin + base;
        float4 a = *(const float4*)src;
        float4 d = *(const float4*)(src + 4);
        pv[0] = __float2bfloat16(a.x); pv[1] = __float2bfloat16(a.y);
        pv[2] = __float2bfloat16(a.z); pv[3] = __float2bfloat16(a.w);
        pv[4] = __float2bfloat16(d.x); pv[5] = __float2bfloat16(d.y);
        pv[6] = __float2bfloat16(d.z); pv[7] = __float2bfloat16(d.w);
    } else {
        uint4 v = *(const uint4*)((const bf16*)xin + base);
        const bf16* q = (const bf16*)&v;
#pragma unroll
        for (int j = 0; j < 8; ++j) pv[j] = q[j];
    }
    bf16* dst = xT + ((size_t)b * NSP + n8 * 8) * CIN + c;
#pragma unroll
    for (int j = 0; j < 8; ++j) dst[(size_t)j * CIN] = pv[j];
}

// ---- GEMM  C[b][m][n] = A[m][k] * BT[b][n][k], K=128, 128x128 tiles ----------
__global__ __launch_bounds__(256) void k_gemm_bt(const bf16* __restrict__ A,
                                                 const bf16* __restrict__ BT,
                                                 void* __restrict__ Cout,
                                                 int Mtotal,
                                                 const int* __restrict__ flagp,
                                                 int mblocks)
{
    __shared__ __align__(16) bf16 lA[128 * CIN];
    __shared__ __align__(16) bf16 lB[128 * CIN];
    int b = blockIdx.z;
    int bx = blockIdx.x;
    int mb, nb;
    if (mblocks == 3) {
        int g = bx / 24, w = bx % 24;
        nb = g * 8 + (w & 7);
        mb = w >> 3;
    } else { mb = 0; nb = bx; }
    size_t nbase = (size_t)nb * 128;
    const bf16* gA = A + (size_t)mb * 128 * CIN;
    const bf16* gB = BT + ((size_t)b * NSP + nbase) * CIN;
    int t = threadIdx.x;
#pragma unroll
    for (int i = 0; i < 8; ++i) {
        int off = (i * 256 + t) * 8;
        *(uint4*)&lA[off] = *(const uint4*)&gA[off];
        *(uint4*)&lB[off] = *(const uint4*)&gB[off];
    }
    __syncthreads();

    int wave = t >> 6, lane = t & 63;
    int wm = (wave & 1) * 64, wn = (wave >> 1) * 64;
    int lr = lane & 15, lq = lane >> 4;
    f32x4 acc[4][4];
#pragma unroll
    for (int mi = 0; mi < 4; ++mi)
#pragma unroll
        for (int ni = 0; ni < 4; ++ni) acc[mi][ni] = (f32x4){0.f, 0.f, 0.f, 0.f};

#pragma unroll
    for (int ks = 0; ks < 4; ++ks) {
        int kof = ks * 32 + lq * 8;
        bf16x8 af[4], bfv[4];
#pragma unroll
        for (int mi = 0; mi < 4; ++mi)
            af[mi] = *(const bf16x8*)&lA[(wm + mi * 16 + lr) * CIN + kof];
#pragma unroll
        for (int ni = 0; ni < 4; ++ni)
            bfv[ni] = *(const bf16x8*)&lB[(wn + ni * 16 + lr) * CIN + kof];
#pragma unroll
        for (int mi = 0; mi < 4; ++mi)
#pragma unroll
            for (int ni = 0; ni < 4; ++ni)
                acc[mi][ni] = __builtin_amdgcn_mfma_f32_16x16x32_bf16(
                    af[mi], bfv[ni], acc[mi][ni], 0, 0, 0);
    }

    int f32o = flagp ? *flagp : 0;
    size_t cb = ((size_t)b * Mtotal + (size_t)mb * 128) * NSP + nbase;
    if (f32o) {
        float* Cb = (float*)Cout + cb;
#pragma unroll
        for (int mi = 0; mi < 4; ++mi)
#pragma unroll
            for (int ni = 0; ni < 4; ++ni)
#pragma unroll
                for (int r = 0; r < 4; ++r)
                    Cb[(size_t)(wm + mi * 16 + lq * 4 + r) * NSP + wn + ni * 16 + lr]
                        = acc[mi][ni][r];
    } else {
        bf16* Cb = (bf16*)Cout + cb;
#pragma unroll
        for (int mi = 0; mi < 4; ++mi)
#pragma unroll
            for (int ni = 0; ni < 4; ++ni)
#pragma unroll
                for (int r = 0; r < 4; ++r)
                    Cb[(size_t)(wm + mi * 16 + lq * 4 + r) * NSP + wn + ni * 16 + lr]
                        = __float2bfloat16(acc[mi][ni][r]);
    }
}

// ---- K2: depthwise 3x3x3 conv ------------------------------------------------
// Round-0 compute structure (6-z slabs, 4-wide strips, scalar FMA) with:
//  * 96B LDS rows (no d-halo cols) -> LDS 38.4KB -> 4 blocks/CU; conflicts
//    measured 5.3e6 (was 1.76e7 at 128B rows)
//  * reg-staged linear copy (uint4 load -> ds_write_b128; plane interior is
//    one contiguous 4608B run). NOTE: global_load_lds with a lane-dependent
//    LDS pointer waterfalls (R2: 15x HBM amplification) — do not reintroduce.
//  * zero phase only for y-halo rows + pads + z-edge planes (~1.7KB, was 51KB)
//  * d-edge columns handled by cndmask (c4==0 / c4==44)
// Plane layout (elements): 8 head pad | 8 planes x (50 rows x 48) | 8 tail pad.
#define PLE 2400        // 50*48 elements per plane
__global__ __launch_bounds__(256, 4) void k_dwconv(const bf16* __restrict__ qkv1,
                                                   const bf16* __restrict__ dw,
                                                   bf16* __restrict__ qkv2,
                                                   float* __restrict__ sums)
{
    __shared__ __align__(16) bf16 lds[16 + 8 * PLE];   // 38432 B
    __shared__ float red[4];
    int bc = blockIdx.x;
    int slab = blockIdx.y;
    int z0 = slab * 6;
    int ch = bc % C3;
    int t = threadIdx.x;
    const bf16* src = qkv1 + (size_t)bc * NSP;
    bf16* dst = qkv2 + (size_t)bc * NSP;

    float wgt[27];
#pragma unroll
    for (int i = 0; i < 27; ++i) wgt[i] = ldb(&dw[ch * 27 + i]);

    // phase 0a: zero pads + y-halo rows (98 x uint4)
    if (t < 98) {
        int e;
        if (t == 0)       e = 0;                 // head pad
        else if (t == 97) e = 8 + 8 * PLE;       // tail pad
        else {
            int j = t - 1;                        // 0..95
            int p = j / 12, r12 = j - p * 12;
            int rr = r12 / 6, q = r12 - rr * 6;   // rr: 0=row0, 1=row49
            e = 8 + p * PLE + rr * 2352 + q * 8;  // 49*48 = 2352
        }
        *(uint4*)&lds[e] = (uint4){0, 0, 0, 0};
    }
    // phase 0b: zero z-edge plane (only slabs 0 and 7)
    if (slab == 0 || slab == 7) {
        int p = (slab == 0) ? 0 : 7;
        bf16* pb = lds + 8 + p * PLE;
        for (int k = t; k < 300; k += 256)
            *(uint4*)&pb[k * 8] = (uint4){0, 0, 0, 0};
    }

    // phase 1: stage 8 plane interiors, reg-staged linear copy.
    // Interior of LDS plane p = elements [48, 48+2304) after plane base, which
    // equals global plane zp elements [0, 2304). 288 uint4 per plane, 2304
    // total = 9 per thread; consecutive lanes -> consecutive 16B (coalesced
    // global loads, conflict-free ds_writes).
    {
        uint4 stg[9];
        int pp[9], rr[9];
#pragma unroll
        for (int i = 0; i < 9; ++i) {
            int vidx = i * 256 + t;               // 0..2303
            int p = vidx >> 8; p = vidx / 288;    // plane 0..7
            int r = vidx - p * 288;               // chunk within plane
            pp[i] = p; rr[i] = r;
            int zp = z0 - 1 + p;
            stg[i] = (uint4){0, 0, 0, 0};
            if ((unsigned)zp < SD)
                stg[i] = *(const uint4*)&src[(size_t)zp * SD2 + r * 8];
        }
#pragma unroll
        for (int i = 0; i < 9; ++i) {
            int zp = z0 - 1 + pp[i];
            if ((unsigned)zp < SD)
                *(uint4*)&lds[8 + pp[i] * PLE + 48 + rr[i] * 8] = stg[i];
        }
    }
    __syncthreads();

    // phase 2: 576 strips: s -> y = s/12, d-base c4 = (s%12)*4
    float ssq = 0.f;
#pragma unroll 1
    for (int r = 0; r < 3; ++r) {
        int s = r * 256 + t;
        if (s < 576) {
            int y = s / 12;
            int c4 = (s - y * 12) * 4;
            float acc[6][4];
#pragma unroll
            for (int oz = 0; oz < 6; ++oz)
#pragma unroll
                for (int d = 0; d < 4; ++d) acc[oz][d] = 0.f;

#pragma unroll
            for (int pl = 0; pl < 8; ++pl) {
                const uint16_t* P =
                    (const uint16_t*)lds + 8 + pl * PLE + y * 48 + c4;
                float v[3][6];
#pragma unroll
                for (int dy = 0; dy < 3; ++dy) {
                    const uint16_t* R = P + dy * 48;
                    uint2 m = *(const uint2*)R;            // cols c4..c4+3 (8B aligned)
                    v[dy][0] = (c4 == 0)  ? 0.f : b2f(R[-1]);
                    v[dy][1] = b2f((uint16_t)m.x);
                    v[dy][2] = b2f((uint16_t)(m.x >> 16));
                    v[dy][3] = b2f((uint16_t)m.y);
                    v[dy][4] = b2f((uint16_t)(m.y >> 16));
                    v[dy][5] = (c4 == 44) ? 0.f : b2f(R[4]);
                }
                float p0[4] = {0.f,0.f,0.f,0.f};
                float p1[4] = {0.f,0.f,0.f,0.f};
                float p2[4] = {0.f,0.f,0.f,0.f};
#pragma unroll
                for (int dy = 0; dy < 3; ++dy)
#pragma unroll
                    for (int dd = 0; dd < 3; ++dd) {
                        float w0 = wgt[dy * 3 + dd];
                        float w1 = wgt[9 + dy * 3 + dd];
                        float w2 = wgt[18 + dy * 3 + dd];
#pragma unroll
                        for (int d = 0; d < 4; ++d) {
                            float xv = v[dy][d + dd];
                            if (pl <= 5)            p0[d] += w0 * xv;
                            if (pl >= 1 && pl <= 6) p1[d] += w1 * xv;
                            if (pl >= 2)            p2[d] += w2 * xv;
                        }
                    }
#pragma unroll
                for (int d = 0; d < 4; ++d) {
                    if (pl <= 5)            acc[pl][d]     += p0[d];
                    if (pl >= 1 && pl <= 6) acc[pl - 1][d] += p1[d];
                    if (pl >= 2)            acc[pl - 2][d] += p2[d];
                }
            }
#pragma unroll
            for (int oz = 0; oz < 6; ++oz) {
                uint16_t u0 = f2b(acc[oz][0]), u1 = f2b(acc[oz][1]);
                uint16_t u2 = f2b(acc[oz][2]), u3 = f2b(acc[oz][3]);
                uint2 o;
                o.x = (uint32_t)u0 | ((uint32_t)u1 << 16);
                o.y = (uint32_t)u2 | ((uint32_t)u3 << 16);
                *(uint2*)&dst[(size_t)(z0 + oz) * SD2 + y * SD + c4] = o;
#pragma unroll
                for (int d = 0; d < 4; ++d) ssq += acc[oz][d] * acc[oz][d];
            }
        }
    }

    for (int off = 32; off; off >>= 1) ssq += __shfl_down(ssq, off, 64);
    if ((t & 63) == 0) red[t >> 6] = ssq;
    __syncthreads();
    if (t == 0) atomicAdd(&sums[bc], red[0] + red[1] + red[2] + red[3]);
}

// ---- K3: scores S[b][h][i][j] = sum_n q_i k_j  (MFMA, full n coverage) -------
__global__ __launch_bounds__(256) void k_scores(const bf16* __restrict__ qkv2,
                                                float* __restrict__ scores)
{
    int b = blockIdx.z, h = blockIdx.y;
    const bf16* qb = qkv2 + ((size_t)b * C3 + h * 16) * NSP;
    const bf16* kb = qkv2 + ((size_t)b * C3 + 128 + h * 16) * NSP;
    int t = threadIdx.x, w = t >> 6, lane = t & 63;
    int m = lane & 15, q4 = lane >> 4;
    size_t n0 = (size_t)blockIdx.x * 1024 + (size_t)w * 256 + (size_t)q4 * 8;
    const bf16* qp = qb + (size_t)m * NSP + n0;
    const bf16* kp = kb + (size_t)m * NSP + n0;
    f32x4 acc = (f32x4){0.f, 0.f, 0.f, 0.f};
#pragma unroll
    for (int it = 0; it < 8; ++it) {
        bf16x8 a  = *(const bf16x8*)(qp + it * 32);
        bf16x8 bb = *(const bf16x8*)(kp + it * 32);
        acc = __builtin_amdgcn_mfma_f32_16x16x32_bf16(a, bb, acc, 0, 0, 0);
    }
    float* srow = scores + (size_t)(b * NH + h) * 256;
#pragma unroll
    for (int r = 0; r < 4; ++r)
        atomicAdd(&srow[(q4 * 4 + r) * 16 + m], acc[r]);
}

// ---- K4: normalize + temperature + softmax -----------------------------------
__global__ void k_softmax(const float* __restrict__ scores,
                          const float* __restrict__ sums,
                          const bf16* __restrict__ temp,
                          float* __restrict__ attn)
{
    int t = threadIdx.x;             // t = b*128 + h*16 + i
    int h = (t >> 4) & 7, b = t >> 7;
    float tau = __bfloat162float(temp[h]);
    float invq = 1.f / fmaxf(sqrtf(sums[b * C3 + (t & 127)]), 1e-12f);
    const float* srow = scores + (size_t)t * 16;
    float s[16]; float mx = -3.4e38f;
#pragma unroll
    for (int j = 0; j < 16; ++j) {
        float invk = 1.f / fmaxf(sqrtf(sums[b * C3 + 128 + h * 16 + j]), 1e-12f);
        s[j] = srow[j] * invq * invk * tau;
        mx = fmaxf(mx, s[j]);
    }
    float sum = 0.f;
#pragma unroll
    for (int j = 0; j < 16; ++j) { s[j] = expf(s[j] - mx); sum += s[j]; }
    float inv = 1.f / sum;
    float* arow = attn + (size_t)t * 16;
#pragma unroll
    for (int j = 0; j < 16; ++j) arow[j] = s[j] * inv;
}

// ---- K5: outT[b][n][h*16+i] = sum_j attn[i][j] v[j][n] -----------------------
__global__ __launch_bounds__(256) void k_av(const bf16* __restrict__ qkv2,
                                            const float* __restrict__ attn,
                                            bf16* __restrict__ outT)
{
    int b = blockIdx.z, h = blockIdx.y;
    const bf16* vb = qkv2 + ((size_t)b * C3 + 256 + h * 16) * NSP;
    __shared__ float at[256];        // at[j*16+i]
    int t = threadIdx.x;
    {
        int i = t >> 4, j = t & 15;
        at[j * 16 + i] = attn[(size_t)(b * NH + h) * 256 + t];
    }
    __syncthreads();
    size_t n0 = (size_t)blockIdx.x * 1024 + (size_t)t * 4;
    float acc[16][4];
#pragma unroll
    for (int i = 0; i < 16; ++i)
#pragma unroll
        for (int k = 0; k < 4; ++k) acc[i][k] = 0.f;
#pragma unroll
    for (int j = 0; j < 16; ++j) {
        uint2 raw = *(const uint2*)&vb[(size_t)j * NSP + n0];
        const bf16* rp = (const bf16*)&raw;
        float vf[4];
#pragma unroll
        for (int k = 0; k < 4; ++k) vf[k] = ldb(&rp[k]);
#pragma unroll
        for (int i = 0; i < 16; ++i) {
            float wv = at[j * 16 + i];
#pragma unroll
            for (int k = 0; k < 4; ++k) acc[i][k] += wv * vf[k];
        }
    }
    bf16* ob = outT + ((size_t)b * NSP + n0) * CIN + h * 16;
#pragma unroll
    for (int k = 0; k < 4; ++k) {
        bf16 tmp[16];
#pragma unroll
        for (int i = 0; i < 16; ++i) tmp[i] = __float2bfloat16(acc[i][k]);
        *(uint4*)&ob[(size_t)k * CIN]     = *(uint4*)&tmp[0];
        *(uint4*)&ob[(size_t)k * CIN + 8] = *(uint4*)&tmp[8];
    }
}

// ---- host --------------------------------------------------------------------
extern "C" void kernel_launch(void* const* d_in, const int* in_sizes, int n_in,
                              void* d_out, int out_size, void* d_ws, size_t ws_size,
                              hipStream_t stream)
{
    const void *px = nullptr, *pq = nullptr, *pd = nullptr, *pp = nullptr, *pt = nullptr;
    for (int i = 0; i < n_in; ++i) {
        switch (in_sizes[i]) {
            case 28311552: px = d_in[i]; break;   // x
            case 49152:    pq = d_in[i]; break;   // qkv_w
            case 10368:    pd = d_in[i]; break;   // dw_w
            case 16384:    pp = d_in[i]; break;   // proj_w
            case 8:        pt = d_in[i]; break;   // temperature
        }
    }
    const size_t required = NQ * 4 + (1u << 20);
    if (!px || !pq || !pd || !pp || !pt || ws_size < required) {
        (void)hipMemsetAsync(d_out, 0, (size_t)out_size * 2, stream);
        return;
    }

    char* ws = (char*)d_ws;
    bf16* qkv1 = (bf16*)ws;                       // NQ bf16
    bf16* qkv2 = (bf16*)(ws + NQ * 2);            // NQ bf16
    char* small = ws + NQ * 4;
    int*   flag   = (int*)small;
    float* sums   = (float*)(small + 256);
    float* scores = (float*)(small + 8192);
    float* attn   = (float*)(small + 24576);
    bf16*  wbuf   = (bf16*)(small + 40960);
    bf16* xT   = qkv2;   // alias: dead before k_dwconv writes qkv2
    bf16* outT = qkv1;   // alias: qkv1 dead after k_dwconv

    (void)hipMemsetAsync(small, 0, 40960, stream);  // flag, sums, scores, attn
    k_sniff<<<1, 256, 0, stream>>>((const uint16_t*)px, flag);
    k_cvtw<<<(WTOTAL + 255) / 256, 256, 0, stream>>>(pq, pd, pp, pt, wbuf, flag);
    k_transpose<<<dim3(6912, NB), 256, 0, stream>>>(px, xT, flag);
    k_gemm_bt<<<dim3(864 * 3, 1, NB), 256, 0, stream>>>(
        wbuf + WOFF_QKVW, xT, qkv1, C3, nullptr, 3);
    k_dwconv<<<dim3(NB * C3, 8), 256, 0, stream>>>(qkv1, wbuf + WOFF_DWW, qkv2, sums);
    k_scores<<<dim3(108, NH, NB), 256, 0, stream>>>(qkv2, scores);
    k_softmax<<<1, 256, 0, stream>>>(scores, sums, wbuf + WOFF_TEMP, attn);
    k_av<<<dim3(108, NH, NB), 256, 0, stream>>>(qkv2, attn, outT);
    k_gemm_bt<<<dim3(864, 1, NB), 256, 0, stream>>>(
        wbuf + WOFF_PROJ, outT, d_out, CIN, flag, 1);
}

// Round 4
// 605.792 us; speedup vs baseline: 2.3158x; 2.1800x over previous
//
#include <hip/hip_runtime.h>
#include <hip/hip_bf16.h>
#include <stdint.h>
#include <stddef.h>

#define NSP 110592      // 48^3
#define SD  48
#define SD2 2304        // 48*48
#define CIN 128
#define C3  384
#define NH  8
#define NB  2
#define NQ  84934656ull // NB*C3*NSP

typedef __hip_bfloat16 bf16;
typedef __bf16 bf16x8 __attribute__((ext_vector_type(8)));
typedef float  f32x4  __attribute__((ext_vector_type(4)));

// wbuf element offsets (all bf16): qkvw | dww | projw | temp
#define WOFF_QKVW 0
#define WOFF_DWW  49152
#define WOFF_PROJ 59520
#define WOFF_TEMP 75904
#define WTOTAL    75912

__device__ __forceinline__ float ldb(const bf16* p){ return __bfloat162float(*p); }
__device__ __forceinline__ float b2f(uint16_t u){
    union { float f; uint32_t i; } x; x.i = (uint32_t)u << 16; return x.f;
}
__device__ __forceinline__ uint16_t f2b(float f){
    bf16 h = __float2bfloat16(f); return *(uint16_t*)&h;
}

// ---- sniffer: flag=1 if inputs are fp32, 0 if bf16 ---------------------------
__global__ void k_sniff(const uint16_t* __restrict__ x16, int* __restrict__ flag)
{
    int t = threadIdx.x; int cnt = 0;
    for (int i = 0; i < 16; ++i) {
        uint16_t b = x16[(size_t)(t * 16 + i) * 2];   // even halves only
        int e = (b >> 7) & 0xFF;
        if (e >= 100 && e <= 140) ++cnt;              // bf16-exponent-plausible
    }
    for (int off = 32; off; off >>= 1) cnt += __shfl_down(cnt, off, 64);
    __shared__ int s[4];
    if ((t & 63) == 0) s[t >> 6] = cnt;
    __syncthreads();
    if (t == 0) *flag = (s[0] + s[1] + s[2] + s[3] < 2048) ? 1 : 0;
}

// ---- canonicalize all weights to bf16 in wbuf --------------------------------
__global__ void k_cvtw(const void* __restrict__ qw, const void* __restrict__ dw,
                       const void* __restrict__ pw, const void* __restrict__ tw,
                       bf16* __restrict__ wbuf, const int* __restrict__ flagp)
{
    int f = *flagp;
    int idx = blockIdx.x * 256 + threadIdx.x;
    if (idx >= WTOTAL) return;
    const void* src; int off;
    if (idx < WOFF_DWW)      { src = qw; off = idx; }
    else if (idx < WOFF_PROJ){ src = dw; off = idx - WOFF_DWW; }
    else if (idx < WOFF_TEMP){ src = pw; off = idx - WOFF_PROJ; }
    else                     { src = tw; off = idx - WOFF_TEMP; }
    float v = f ? ((const float*)src)[off]
                : __bfloat162float(((const bf16*)src)[off]);
    wbuf[idx] = __float2bfloat16(v);
}

// ---- K0: transpose x[b][c][n] -> xT[b][n][c] (bf16 out, dual-dtype in) -------
__global__ __launch_bounds__(256) void k_transpose(const void* __restrict__ xin,
                                                   bf16* __restrict__ xT,
                                                   const int* __restrict__ flagp)
{
    int f = *flagp;
    int b = blockIdx.y;
    size_t tid = (size_t)blockIdx.x * 256 + threadIdx.x;
    int c = (int)(tid & 127);
    size_t n8 = tid >> 7;
    size_t base = ((size_t)b * CIN + c) * NSP + n8 * 8;
    bf16 pv[8];
    if (f) {
        const float* src = (const float*)xin + base;
        float4 a = *(const float4*)src;
        float4 d = *(const float4*)(src + 4);
        pv[0] = __float2bfloat16(a.x); pv[1] = __float2bfloat16(a.y);
        pv[2] = __float2bfloat16(a.z); pv[3] = __float2bfloat16(a.w);
        pv[4] = __float2bfloat16(d.x); pv[5] = __float2bfloat16(d.y);
        pv[6] = __float2bfloat16(d.z); pv[7] = __float2bfloat16(d.w);
    } else {
        uint4 v = *(const uint4*)((const bf16*)xin + base);
        const bf16* q = (const bf16*)&v;
#pragma unroll
        for (int j = 0; j < 8; ++j) pv[j] = q[j];
    }
    bf16* dst = xT + ((size_t)b * NSP + n8 * 8) * CIN + c;
#pragma unroll
    for (int j = 0; j < 8; ++j) dst[(size_t)j * CIN] = pv[j];
}

// ---- GEMM  C[b][m][n] = A[m][k] * BT[b][n][k], K=128, 128x128 tiles ----------
__global__ __launch_bounds__(256) void k_gemm_bt(const bf16* __restrict__ A,
                                                 const bf16* __restrict__ BT,
                                                 void* __restrict__ Cout,
                                                 int Mtotal,
                                                 const int* __restrict__ flagp,
                                                 int mblocks)
{
    __shared__ __align__(16) bf16 lA[128 * CIN];
    __shared__ __align__(16) bf16 lB[128 * CIN];
    int b = blockIdx.z;
    int bx = blockIdx.x;
    int mb, nb;
    if (mblocks == 3) {
        int g = bx / 24, w = bx % 24;
        nb = g * 8 + (w & 7);
        mb = w >> 3;
    } else { mb = 0; nb = bx; }
    size_t nbase = (size_t)nb * 128;
    const bf16* gA = A + (size_t)mb * 128 * CIN;
    const bf16* gB = BT + ((size_t)b * NSP + nbase) * CIN;
    int t = threadIdx.x;
#pragma unroll
    for (int i = 0; i < 8; ++i) {
        int off = (i * 256 + t) * 8;
        *(uint4*)&lA[off] = *(const uint4*)&gA[off];
        *(uint4*)&lB[off] = *(const uint4*)&gB[off];
    }
    __syncthreads();

    int wave = t >> 6, lane = t & 63;
    int wm = (wave & 1) * 64, wn = (wave >> 1) * 64;
    int lr = lane & 15, lq = lane >> 4;
    f32x4 acc[4][4];
#pragma unroll
    for (int mi = 0; mi < 4; ++mi)
#pragma unroll
        for (int ni = 0; ni < 4; ++ni) acc[mi][ni] = (f32x4){0.f, 0.f, 0.f, 0.f};

#pragma unroll
    for (int ks = 0; ks < 4; ++ks) {
        int kof = ks * 32 + lq * 8;
        bf16x8 af[4], bfv[4];
#pragma unroll
        for (int mi = 0; mi < 4; ++mi)
            af[mi] = *(const bf16x8*)&lA[(wm + mi * 16 + lr) * CIN + kof];
#pragma unroll
        for (int ni = 0; ni < 4; ++ni)
            bfv[ni] = *(const bf16x8*)&lB[(wn + ni * 16 + lr) * CIN + kof];
#pragma unroll
        for (int mi = 0; mi < 4; ++mi)
#pragma unroll
            for (int ni = 0; ni < 4; ++ni)
                acc[mi][ni] = __builtin_amdgcn_mfma_f32_16x16x32_bf16(
                    af[mi], bfv[ni], acc[mi][ni], 0, 0, 0);
    }

    int f32o = flagp ? *flagp : 0;
    size_t cb = ((size_t)b * Mtotal + (size_t)mb * 128) * NSP + nbase;
    if (f32o) {
        float* Cb = (float*)Cout + cb;
#pragma unroll
        for (int mi = 0; mi < 4; ++mi)
#pragma unroll
            for (int ni = 0; ni < 4; ++ni)
#pragma unroll
                for (int r = 0; r < 4; ++r)
                    Cb[(size_t)(wm + mi * 16 + lq * 4 + r) * NSP + wn + ni * 16 + lr]
                        = acc[mi][ni][r];
    } else {
        bf16* Cb = (bf16*)Cout + cb;
#pragma unroll
        for (int mi = 0; mi < 4; ++mi)
#pragma unroll
            for (int ni = 0; ni < 4; ++ni)
#pragma unroll
                for (int r = 0; r < 4; ++r)
                    Cb[(size_t)(wm + mi * 16 + lq * 4 + r) * NSP + wn + ni * 16 + lr]
                        = __float2bfloat16(acc[mi][ni][r]);
    }
}

// ---- K2: depthwise 3x3x3 conv ------------------------------------------------
// Round-0 compute structure (6-z slabs, 4-wide strips, scalar FMA) with:
//  * 96B LDS rows (no d-halo cols) -> LDS 38.4KB -> 4 blocks/CU; conflicts
//    measured 5.3e6 (was 1.76e7 at 128B rows)
//  * zero phase only for y-halo rows + pads + z-edge planes (~1.7KB, was 51KB)
//  * d-edge columns handled by cndmask (c4==0 / c4==44)
// LDS occupancy cap is already 4 blocks/CU; do NOT add a min-waves arg to
// __launch_bounds__: (256,4) squeezed VGPRs 80->64 and spilled the phase-2
// accumulators to scratch (R2/R3: 15x HBM amplification, 924us).
// Plane layout (elements): 8 head pad | 8 planes x (50 rows x 48) | 8 tail pad.
#define PLE 2400        // 50*48 elements per plane
__global__ __launch_bounds__(256) void k_dwconv(const bf16* __restrict__ qkv1,
                                                const bf16* __restrict__ dw,
                                                bf16* __restrict__ qkv2,
                                                float* __restrict__ sums)
{
    __shared__ __align__(16) bf16 lds[16 + 8 * PLE];   // 38432 B
    __shared__ float red[4];
    int bc = blockIdx.x;
    int slab = blockIdx.y;
    int z0 = slab * 6;
    int ch = bc % C3;
    int t = threadIdx.x;
    const bf16* src = qkv1 + (size_t)bc * NSP;
    bf16* dst = qkv2 + (size_t)bc * NSP;

    float wgt[27];
#pragma unroll
    for (int i = 0; i < 27; ++i) wgt[i] = ldb(&dw[ch * 27 + i]);

    // phase 0a: zero pads + y-halo rows (98 x uint4)
    if (t < 98) {
        int e;
        if (t == 0)       e = 0;                 // head pad
        else if (t == 97) e = 8 + 8 * PLE;       // tail pad
        else {
            int j = t - 1;                        // 0..95
            int p = j / 12, r12 = j - p * 12;
            int rr = r12 / 6, q = r12 - rr * 6;   // rr: 0=row0, 1=row49
            e = 8 + p * PLE + rr * 2352 + q * 8;  // 49*48 = 2352
        }
        *(uint4*)&lds[e] = (uint4){0, 0, 0, 0};
    }
    // phase 0b: zero z-edge plane (only slabs 0 and 7)
    if (slab == 0 || slab == 7) {
        int p = (slab == 0) ? 0 : 7;
        bf16* pb = lds + 8 + p * PLE;
        for (int k = t; k < 300; k += 256)
            *(uint4*)&pb[k * 8] = (uint4){0, 0, 0, 0};
    }

    // phase 1: stage 8 plane interiors, fused load->store linear copy
    // (plane interior = one contiguous 4608B run; 288 uint4 per plane, 2304
    // total = 9 per thread; consecutive lanes -> consecutive 16B).
#pragma unroll
    for (int i = 0; i < 9; ++i) {
        int vidx = i * 256 + t;                   // 0..2303
        int p = vidx / 288;                       // plane 0..7
        int r = vidx - p * 288;                   // chunk within plane
        int zp = z0 - 1 + p;
        if ((unsigned)zp < SD) {
            uint4 v = *(const uint4*)&src[(size_t)zp * SD2 + r * 8];
            *(uint4*)&lds[8 + p * PLE + 48 + r * 8] = v;
        }
    }
    __syncthreads();

    // phase 2: 576 strips: s -> y = s/12, d-base c4 = (s%12)*4
    float ssq = 0.f;
#pragma unroll 1
    for (int r = 0; r < 3; ++r) {
        int s = r * 256 + t;
        if (s < 576) {
            int y = s / 12;
            int c4 = (s - y * 12) * 4;
            float acc[6][4];
#pragma unroll
            for (int oz = 0; oz < 6; ++oz)
#pragma unroll
                for (int d = 0; d < 4; ++d) acc[oz][d] = 0.f;

#pragma unroll
            for (int pl = 0; pl < 8; ++pl) {
                const uint16_t* P =
                    (const uint16_t*)lds + 8 + pl * PLE + y * 48 + c4;
                float v[3][6];
#pragma unroll
                for (int dy = 0; dy < 3; ++dy) {
                    const uint16_t* R = P + dy * 48;
                    uint2 m = *(const uint2*)R;            // cols c4..c4+3 (8B aligned)
                    v[dy][0] = (c4 == 0)  ? 0.f : b2f(R[-1]);
                    v[dy][1] = b2f((uint16_t)m.x);
                    v[dy][2] = b2f((uint16_t)(m.x >> 16));
                    v[dy][3] = b2f((uint16_t)m.y);
                    v[dy][4] = b2f((uint16_t)(m.y >> 16));
                    v[dy][5] = (c4 == 44) ? 0.f : b2f(R[4]);
                }
                float p0[4] = {0.f,0.f,0.f,0.f};
                float p1[4] = {0.f,0.f,0.f,0.f};
                float p2[4] = {0.f,0.f,0.f,0.f};
#pragma unroll
                for (int dy = 0; dy < 3; ++dy)
#pragma unroll
                    for (int dd = 0; dd < 3; ++dd) {
                        float w0 = wgt[dy * 3 + dd];
                        float w1 = wgt[9 + dy * 3 + dd];
                        float w2 = wgt[18 + dy * 3 + dd];
#pragma unroll
                        for (int d = 0; d < 4; ++d) {
                            float xv = v[dy][d + dd];
                            if (pl <= 5)            p0[d] += w0 * xv;
                            if (pl >= 1 && pl <= 6) p1[d] += w1 * xv;
                            if (pl >= 2)            p2[d] += w2 * xv;
                        }
                    }
#pragma unroll
                for (int d = 0; d < 4; ++d) {
                    if (pl <= 5)            acc[pl][d]     += p0[d];
                    if (pl >= 1 && pl <= 6) acc[pl - 1][d] += p1[d];
                    if (pl >= 2)            acc[pl - 2][d] += p2[d];
                }
            }
#pragma unroll
            for (int oz = 0; oz < 6; ++oz) {
                uint16_t u0 = f2b(acc[oz][0]), u1 = f2b(acc[oz][1]);
                uint16_t u2 = f2b(acc[oz][2]), u3 = f2b(acc[oz][3]);
                uint2 o;
                o.x = (uint32_t)u0 | ((uint32_t)u1 << 16);
                o.y = (uint32_t)u2 | ((uint32_t)u3 << 16);
                *(uint2*)&dst[(size_t)(z0 + oz) * SD2 + y * SD + c4] = o;
#pragma unroll
                for (int d = 0; d < 4; ++d) ssq += acc[oz][d] * acc[oz][d];
            }
        }
    }

    for (int off = 32; off; off >>= 1) ssq += __shfl_down(ssq, off, 64);
    if ((t & 63) == 0) red[t >> 6] = ssq;
    __syncthreads();
    if (t == 0) atomicAdd(&sums[bc], red[0] + red[1] + red[2] + red[3]);
}

// ---- K3: scores S[b][h][i][j] = sum_n q_i k_j  (MFMA, full n coverage) -------
__global__ __launch_bounds__(256) void k_scores(const bf16* __restrict__ qkv2,
                                                float* __restrict__ scores)
{
    int b = blockIdx.z, h = blockIdx.y;
    const bf16* qb = qkv2 + ((size_t)b * C3 + h * 16) * NSP;
    const bf16* kb = qkv2 + ((size_t)b * C3 + 128 + h * 16) * NSP;
    int t = threadIdx.x, w = t >> 6, lane = t & 63;
    int m = lane & 15, q4 = lane >> 4;
    size_t n0 = (size_t)blockIdx.x * 1024 + (size_t)w * 256 + (size_t)q4 * 8;
    const bf16* qp = qb + (size_t)m * NSP + n0;
    const bf16* kp = kb + (size_t)m * NSP + n0;
    f32x4 acc = (f32x4){0.f, 0.f, 0.f, 0.f};
#pragma unroll
    for (int it = 0; it < 8; ++it) {
        bf16x8 a  = *(const bf16x8*)(qp + it * 32);
        bf16x8 bb = *(const bf16x8*)(kp + it * 32);
        acc = __builtin_amdgcn_mfma_f32_16x16x32_bf16(a, bb, acc, 0, 0, 0);
    }
    float* srow = scores + (size_t)(b * NH + h) * 256;
#pragma unroll
    for (int r = 0; r < 4; ++r)
        atomicAdd(&srow[(q4 * 4 + r) * 16 + m], acc[r]);
}

// ---- K4: normalize + temperature + softmax -----------------------------------
__global__ void k_softmax(const float* __restrict__ scores,
                          const float* __restrict__ sums,
                          const bf16* __restrict__ temp,
                          float* __restrict__ attn)
{
    int t = threadIdx.x;             // t = b*128 + h*16 + i
    int h = (t >> 4) & 7, b = t >> 7;
    float tau = __bfloat162float(temp[h]);
    float invq = 1.f / fmaxf(sqrtf(sums[b * C3 + (t & 127)]), 1e-12f);
    const float* srow = scores + (size_t)t * 16;
    float s[16]; float mx = -3.4e38f;
#pragma unroll
    for (int j = 0; j < 16; ++j) {
        float invk = 1.f / fmaxf(sqrtf(sums[b * C3 + 128 + h * 16 + j]), 1e-12f);
        s[j] = srow[j] * invq * invk * tau;
        mx = fmaxf(mx, s[j]);
    }
    float sum = 0.f;
#pragma unroll
    for (int j = 0; j < 16; ++j) { s[j] = expf(s[j] - mx); sum += s[j]; }
    float inv = 1.f / sum;
    float* arow = attn + (size_t)t * 16;
#pragma unroll
    for (int j = 0; j < 16; ++j) arow[j] = s[j] * inv;
}

// ---- K5: outT[b][n][h*16+i] = sum_j attn[i][j] v[j][n] -----------------------
__global__ __launch_bounds__(256) void k_av(const bf16* __restrict__ qkv2,
                                            const float* __restrict__ attn,
                                            bf16* __restrict__ outT)
{
    int b = blockIdx.z, h = blockIdx.y;
    const bf16* vb = qkv2 + ((size_t)b * C3 + 256 + h * 16) * NSP;
    __shared__ float at[256];        // at[j*16+i]
    int t = threadIdx.x;
    {
        int i = t >> 4, j = t & 15;
        at[j * 16 + i] = attn[(size_t)(b * NH + h) * 256 + t];
    }
    __syncthreads();
    size_t n0 = (size_t)blockIdx.x * 1024 + (size_t)t * 4;
    float acc[16][4];
#pragma unroll
    for (int i = 0; i < 16; ++i)
#pragma unroll
        for (int k = 0; k < 4; ++k) acc[i][k] = 0.f;
#pragma unroll
    for (int j = 0; j < 16; ++j) {
        uint2 raw = *(const uint2*)&vb[(size_t)j * NSP + n0];
        const bf16* rp = (const bf16*)&raw;
        float vf[4];
#pragma unroll
        for (int k = 0; k < 4; ++k) vf[k] = ldb(&rp[k]);
#pragma unroll
        for (int i = 0; i < 16; ++i) {
            float wv = at[j * 16 + i];
#pragma unroll
            for (int k = 0; k < 4; ++k) acc[i][k] += wv * vf[k];
        }
    }
    bf16* ob = outT + ((size_t)b * NSP + n0) * CIN + h * 16;
#pragma unroll
    for (int k = 0; k < 4; ++k) {
        bf16 tmp[16];
#pragma unroll
        for (int i = 0; i < 16; ++i) tmp[i] = __float2bfloat16(acc[i][k]);
        *(uint4*)&ob[(size_t)k * CIN]     = *(uint4*)&tmp[0];
        *(uint4*)&ob[(size_t)k * CIN + 8] = *(uint4*)&tmp[8];
    }
}

// ---- host --------------------------------------------------------------------
extern "C" void kernel_launch(void* const* d_in, const int* in_sizes, int n_in,
                              void* d_out, int out_size, void* d_ws, size_t ws_size,
                              hipStream_t stream)
{
    const void *px = nullptr, *pq = nullptr, *pd = nullptr, *pp = nullptr, *pt = nullptr;
    for (int i = 0; i < n_in; ++i) {
        switch (in_sizes[i]) {
            case 28311552: px = d_in[i]; break;   // x
            case 49152:    pq = d_in[i]; break;   // qkv_w
            case 10368:    pd = d_in[i]; break;   // dw_w
            case 16384:    pp = d_in[i]; break;   // proj_w
            case 8:        pt = d_in[i]; break;   // temperature
        }
    }
    const size_t required = NQ * 4 + (1u << 20);
    if (!px || !pq || !pd || !pp || !pt || ws_size < required) {
        (void)hipMemsetAsync(d_out, 0, (size_t)out_size * 2, stream);
        return;
    }

    char* ws = (char*)d_ws;
    bf16* qkv1 = (bf16*)ws;                       // NQ bf16
    bf16* qkv2 = (bf16*)(ws + NQ * 2);            // NQ bf16
    char* small = ws + NQ * 4;
    int*   flag   = (int*)small;
    float* sums   = (float*)(small + 256);
    float* scores = (float*)(small + 8192);
    float* attn   = (float*)(small + 24576);
    bf16*  wbuf   = (bf16*)(small + 40960);
    bf16* xT   = qkv2;   // alias: dead before k_dwconv writes qkv2
    bf16* outT = qkv1;   // alias: qkv1 dead after k_dwconv

    (void)hipMemsetAsync(small, 0, 40960, stream);  // flag, sums, scores, attn
    k_sniff<<<1, 256, 0, stream>>>((const uint16_t*)px, flag);
    k_cvtw<<<(WTOTAL + 255) / 256, 256, 0, stream>>>(pq, pd, pp, pt, wbuf, flag);
    k_transpose<<<dim3(6912, NB), 256, 0, stream>>>(px, xT, flag);
    k_gemm_bt<<<dim3(864 * 3, 1, NB), 256, 0, stream>>>(
        wbuf + WOFF_QKVW, xT, qkv1, C3, nullptr, 3);
    k_dwconv<<<dim3(NB * C3, 8), 256, 0, stream>>>(qkv1, wbuf + WOFF_DWW, qkv2, sums);
    k_scores<<<dim3(108, NH, NB), 256, 0, stream>>>(qkv2, scores);
    k_softmax<<<1, 256, 0, stream>>>(scores, sums, wbuf + WOFF_TEMP, attn);
    k_av<<<dim3(108, NH, NB), 256, 0, stream>>>(qkv2, attn, outT);
    k_gemm_bt<<<dim3(864, 1, NB), 256, 0, stream>>>(
        wbuf + WOFF_PROJ, outT, d_out, CIN, flag, 1);
}

// Round 5
// 533.702 us; speedup vs baseline: 2.6286x; 1.1351x over previous
//
#include <hip/hip_runtime.h>
#include <hip/hip_bf16.h>
#include <stdint.h>
#include <stddef.h>

#define NSP 110592      // 48^3
#define SD  48
#define SD2 2304        // 48*48
#define CIN 128
#define C3  384
#define NH  8
#define NB  2
#define NQ  84934656ull // NB*C3*NSP

typedef __hip_bfloat16 bf16;
typedef __bf16 bf16x8 __attribute__((ext_vector_type(8)));
typedef float  f32x4  __attribute__((ext_vector_type(4)));

// wbuf element offsets (all bf16): qkvw | dww | projw | temp
#define WOFF_QKVW 0
#define WOFF_DWW  49152
#define WOFF_PROJ 59520
#define WOFF_TEMP 75904
#define WTOTAL    75912

__device__ __forceinline__ float ldb(const bf16* p){ return __bfloat162float(*p); }
__device__ __forceinline__ float b2f(uint16_t u){
    union { float f; uint32_t i; } x; x.i = (uint32_t)u << 16; return x.f;
}
__device__ __forceinline__ uint16_t f2b(float f){
    bf16 h = __float2bfloat16(f); return *(uint16_t*)&h;
}

// ---- sniffer: flag=1 if inputs are fp32, 0 if bf16 ---------------------------
__global__ void k_sniff(const uint16_t* __restrict__ x16, int* __restrict__ flag)
{
    int t = threadIdx.x; int cnt = 0;
    for (int i = 0; i < 16; ++i) {
        uint16_t b = x16[(size_t)(t * 16 + i) * 2];   // even halves only
        int e = (b >> 7) & 0xFF;
        if (e >= 100 && e <= 140) ++cnt;              // bf16-exponent-plausible
    }
    for (int off = 32; off; off >>= 1) cnt += __shfl_down(cnt, off, 64);
    __shared__ int s[4];
    if ((t & 63) == 0) s[t >> 6] = cnt;
    __syncthreads();
    if (t == 0) *flag = (s[0] + s[1] + s[2] + s[3] < 2048) ? 1 : 0;
}

// ---- canonicalize all weights to bf16 in wbuf --------------------------------
__global__ void k_cvtw(const void* __restrict__ qw, const void* __restrict__ dw,
                       const void* __restrict__ pw, const void* __restrict__ tw,
                       bf16* __restrict__ wbuf, const int* __restrict__ flagp)
{
    int f = *flagp;
    int idx = blockIdx.x * 256 + threadIdx.x;
    if (idx >= WTOTAL) return;
    const void* src; int off;
    if (idx < WOFF_DWW)      { src = qw; off = idx; }
    else if (idx < WOFF_PROJ){ src = dw; off = idx - WOFF_DWW; }
    else if (idx < WOFF_TEMP){ src = pw; off = idx - WOFF_PROJ; }
    else                     { src = tw; off = idx - WOFF_TEMP; }
    float v = f ? ((const float*)src)[off]
                : __bfloat162float(((const bf16*)src)[off]);
    wbuf[idx] = __float2bfloat16(v);
}

// ---- K1a: qkv GEMM with fused x-transpose staging ----------------------------
// C[b][m][n] = A[m][k] * x[b][k][n], K=128, 128x128 tiles, bf16 out.
// B-tile staged directly from x (fp32 or bf16 per flag): coalesced reads along
// n, 4x4 register transpose, ds_write_b64 into lB[n][c]. MFMA loop, LDS layout
// (128-elem rows) and C-write are byte-identical to the verified k_gemm_bt.
// Replaces the separate k_transpose kernel (saves its 170MB of HBM traffic).
__global__ __launch_bounds__(256) void k_gemm_qkv(const bf16* __restrict__ A,
                                                  const void* __restrict__ X,
                                                  bf16* __restrict__ Cout,
                                                  const int* __restrict__ flagp)
{
    __shared__ __align__(16) bf16 lA[128 * CIN];
    __shared__ __align__(16) bf16 lB[128 * CIN];
    int f = *flagp;
    int b = blockIdx.z;
    int bx = blockIdx.x;
    int g = bx / 24, w = bx % 24;
    int nb = g * 8 + (w & 7);          // mb-peers 8 blocks apart -> same XCD,
    int mb = w >> 3;                   // share the x tile in L2
    size_t nbase = (size_t)nb * 128;
    const bf16* gA = A + (size_t)mb * 128 * CIN;
    int t = threadIdx.x;

    // stage A (linear): 2048 uint4 = 8 per thread
#pragma unroll
    for (int i = 0; i < 8; ++i) {
        int idx = i * 256 + t;
        int r = idx >> 4, cc = idx & 15;
        *(uint4*)&lA[r * CIN + cc * 8] = *(const uint4*)&gA[r * CIN + cc * 8];
    }

    // stage B transposed from x[b][c][n]: thread (cq,nq) does 4 passes of a
    // 4(row)x4(col) micro-tile: 4 coalesced row loads -> 4 ds_write_b64.
    int cq = t >> 5;                   // 0..7
    int nq = t & 31;                   // 0..31
    if (f) {
        const float* xb = (const float*)X + (size_t)b * CIN * NSP + nbase;
#pragma unroll
        for (int p = 0; p < 4; ++p) {
            int c0 = p * 32 + cq * 4;
            float4 rv[4];
#pragma unroll
            for (int r = 0; r < 4; ++r)
                rv[r] = *(const float4*)&xb[(size_t)(c0 + r) * NSP + nq * 4];
#pragma unroll
            for (int e = 0; e < 4; ++e) {
                ushort4 o;
                o.x = f2b(((const float*)&rv[0])[e]);
                o.y = f2b(((const float*)&rv[1])[e]);
                o.z = f2b(((const float*)&rv[2])[e]);
                o.w = f2b(((const float*)&rv[3])[e]);
                *(ushort4*)&lB[(nq * 4 + e) * CIN + c0] = o;
            }
        }
    } else {
        const bf16* xb = (const bf16*)X + (size_t)b * CIN * NSP + nbase;
#pragma unroll
        for (int p = 0; p < 4; ++p) {
            int c0 = p * 32 + cq * 4;
            uint2 rv[4];
#pragma unroll
            for (int r = 0; r < 4; ++r)
                rv[r] = *(const uint2*)&xb[(size_t)(c0 + r) * NSP + nq * 4];
#pragma unroll
            for (int e = 0; e < 4; ++e) {
                ushort4 o;
                o.x = (uint16_t)(e < 2 ? (rv[0].x >> (e * 16)) : (rv[0].y >> ((e - 2) * 16)));
                o.y = (uint16_t)(e < 2 ? (rv[1].x >> (e * 16)) : (rv[1].y >> ((e - 2) * 16)));
                o.z = (uint16_t)(e < 2 ? (rv[2].x >> (e * 16)) : (rv[2].y >> ((e - 2) * 16)));
                o.w = (uint16_t)(e < 2 ? (rv[3].x >> (e * 16)) : (rv[3].y >> ((e - 2) * 16)));
                *(ushort4*)&lB[(nq * 4 + e) * CIN + c0] = o;
            }
        }
    }
    __syncthreads();

    int wave = t >> 6, lane = t & 63;
    int wm = (wave & 1) * 64, wn = (wave >> 1) * 64;
    int lr = lane & 15, lq = lane >> 4;
    f32x4 acc[4][4];
#pragma unroll
    for (int mi = 0; mi < 4; ++mi)
#pragma unroll
        for (int ni = 0; ni < 4; ++ni) acc[mi][ni] = (f32x4){0.f, 0.f, 0.f, 0.f};

#pragma unroll
    for (int ks = 0; ks < 4; ++ks) {
        int kof = ks * 32 + lq * 8;
        bf16x8 af[4], bfv[4];
#pragma unroll
        for (int mi = 0; mi < 4; ++mi)
            af[mi] = *(const bf16x8*)&lA[(wm + mi * 16 + lr) * CIN + kof];
#pragma unroll
        for (int ni = 0; ni < 4; ++ni)
            bfv[ni] = *(const bf16x8*)&lB[(wn + ni * 16 + lr) * CIN + kof];
#pragma unroll
        for (int mi = 0; mi < 4; ++mi)
#pragma unroll
            for (int ni = 0; ni < 4; ++ni)
                acc[mi][ni] = __builtin_amdgcn_mfma_f32_16x16x32_bf16(
                    af[mi], bfv[ni], acc[mi][ni], 0, 0, 0);
    }

    size_t cb = ((size_t)b * C3 + (size_t)mb * 128) * NSP + nbase;
    bf16* Cb = Cout + cb;
#pragma unroll
    for (int mi = 0; mi < 4; ++mi)
#pragma unroll
        for (int ni = 0; ni < 4; ++ni)
#pragma unroll
            for (int r = 0; r < 4; ++r)
                Cb[(size_t)(wm + mi * 16 + lq * 4 + r) * NSP + wn + ni * 16 + lr]
                    = __float2bfloat16(acc[mi][ni][r]);
}

// ---- GEMM  C[b][m][n] = A[m][k] * BT[b][n][k], K=128, 128x128 tiles ----------
// (retained for the proj GEMM; reads outT in [n][c] layout)
__global__ __launch_bounds__(256) void k_gemm_bt(const bf16* __restrict__ A,
                                                 const bf16* __restrict__ BT,
                                                 void* __restrict__ Cout,
                                                 int Mtotal,
                                                 const int* __restrict__ flagp,
                                                 int mblocks)
{
    __shared__ __align__(16) bf16 lA[128 * CIN];
    __shared__ __align__(16) bf16 lB[128 * CIN];
    int b = blockIdx.z;
    int bx = blockIdx.x;
    int mb, nb;
    if (mblocks == 3) {
        int g = bx / 24, w = bx % 24;
        nb = g * 8 + (w & 7);
        mb = w >> 3;
    } else { mb = 0; nb = bx; }
    size_t nbase = (size_t)nb * 128;
    const bf16* gA = A + (size_t)mb * 128 * CIN;
    const bf16* gB = BT + ((size_t)b * NSP + nbase) * CIN;
    int t = threadIdx.x;
#pragma unroll
    for (int i = 0; i < 8; ++i) {
        int off = (i * 256 + t) * 8;
        *(uint4*)&lA[off] = *(const uint4*)&gA[off];
        *(uint4*)&lB[off] = *(const uint4*)&gB[off];
    }
    __syncthreads();

    int wave = t >> 6, lane = t & 63;
    int wm = (wave & 1) * 64, wn = (wave >> 1) * 64;
    int lr = lane & 15, lq = lane >> 4;
    f32x4 acc[4][4];
#pragma unroll
    for (int mi = 0; mi < 4; ++mi)
#pragma unroll
        for (int ni = 0; ni < 4; ++ni) acc[mi][ni] = (f32x4){0.f, 0.f, 0.f, 0.f};

#pragma unroll
    for (int ks = 0; ks < 4; ++ks) {
        int kof = ks * 32 + lq * 8;
        bf16x8 af[4], bfv[4];
#pragma unroll
        for (int mi = 0; mi < 4; ++mi)
            af[mi] = *(const bf16x8*)&lA[(wm + mi * 16 + lr) * CIN + kof];
#pragma unroll
        for (int ni = 0; ni < 4; ++ni)
            bfv[ni] = *(const bf16x8*)&lB[(wn + ni * 16 + lr) * CIN + kof];
#pragma unroll
        for (int mi = 0; mi < 4; ++mi)
#pragma unroll
            for (int ni = 0; ni < 4; ++ni)
                acc[mi][ni] = __builtin_amdgcn_mfma_f32_16x16x32_bf16(
                    af[mi], bfv[ni], acc[mi][ni], 0, 0, 0);
    }

    int f32o = flagp ? *flagp : 0;
    size_t cb = ((size_t)b * Mtotal + (size_t)mb * 128) * NSP + nbase;
    if (f32o) {
        float* Cb = (float*)Cout + cb;
#pragma unroll
        for (int mi = 0; mi < 4; ++mi)
#pragma unroll
            for (int ni = 0; ni < 4; ++ni)
#pragma unroll
                for (int r = 0; r < 4; ++r)
                    Cb[(size_t)(wm + mi * 16 + lq * 4 + r) * NSP + wn + ni * 16 + lr]
                        = acc[mi][ni][r];
    } else {
        bf16* Cb = (bf16*)Cout + cb;
#pragma unroll
        for (int mi = 0; mi < 4; ++mi)
#pragma unroll
            for (int ni = 0; ni < 4; ++ni)
#pragma unroll
                for (int r = 0; r < 4; ++r)
                    Cb[(size_t)(wm + mi * 16 + lq * 4 + r) * NSP + wn + ni * 16 + lr]
                        = __float2bfloat16(acc[mi][ni][r]);
    }
}

// ---- K2: depthwise 3x3x3 conv, LDS-tiled, 4-wide vectorized strips -----------
// EXACT round-0 version (verified 160us, VGPR 80). Landmines found since:
//  * do NOT add a min-waves arg to __launch_bounds__ ((256,4) -> VGPR 64 ->
//    scratch spill in the hot loop -> 15x HBM amplification, 924us)
//  * do NOT use global_load_lds here (lane-dependent LDS dest)
//  * 96B-row/no-halo variant: fewer conflicts but more VGPR + stalls (224us)
#define PLN 3200        // 64*50
__global__ __launch_bounds__(256) void k_dwconv(const bf16* __restrict__ qkv1,
                                                const bf16* __restrict__ dw,
                                                bf16* __restrict__ qkv2,
                                                float* __restrict__ sums)
{
    __shared__ __align__(16) bf16 lds[8 * PLN];
    __shared__ float red[4];
    int bc = blockIdx.x;
    int slab = blockIdx.y;
    int z0 = slab * 6;
    int ch = bc % C3;
    int t = threadIdx.x;
    const bf16* src = qkv1 + (size_t)bc * NSP;
    bf16* dst = qkv2 + (size_t)bc * NSP;

    float wgt[27];
#pragma unroll
    for (int i = 0; i < 27; ++i) wgt[i] = ldb(&dw[ch * 27 + i]);

    // phase 0: zero all of LDS
#pragma unroll
    for (int i = 0; i < 13; ++i) {
        int idx = i * 256 + t;
        if (idx < 3200) *(uint4*)&lds[idx * 8] = (uint4){0, 0, 0, 0};
    }
    __syncthreads();

    // phase 1: stage 8 planes (z0-1 .. z0+6); 288 uint4 per plane
#pragma unroll
    for (int i = 0; i < 9; ++i) {
        int vidx = i * 256 + t;            // 0..2303
        int p = vidx / 288;
        int r = vidx - p * 288;
        int y = r / 6;
        int dg = r - y * 6;
        int zp = z0 - 1 + p;
        if ((unsigned)zp < SD) {
            uint4 v = *(const uint4*)&src[(size_t)zp * SD2 + y * SD + dg * 8];
            *(uint4*)&lds[(p * PLN + (y + 1) * 64 + 8 + dg * 8)] = v;
        }
    }
    __syncthreads();

    // phase 2: strips. 576 strips: strip s -> y = s/12, d-base = (s%12)*4.
    float ssq = 0.f;
#pragma unroll 1
    for (int r = 0; r < 3; ++r) {
        int s = r * 256 + t;
        if (s < 576) {                      // wave-uniform (residual = wave 0)
            int y = s / 12;
            int c4 = (s - y * 12) * 4;
            float acc[6][4];
#pragma unroll
            for (int oz = 0; oz < 6; ++oz)
#pragma unroll
                for (int d = 0; d < 4; ++d) acc[oz][d] = 0.f;

#pragma unroll
            for (int pl = 0; pl < 8; ++pl) {
                const uint16_t* P =
                    (const uint16_t*)lds + pl * PLN + y * 64 + 8 + c4;
                float v[3][6];
#pragma unroll
                for (int dy = 0; dy < 3; ++dy) {
                    const uint16_t* R = P + dy * 64;
                    uint2 m = *(const uint2*)R;            // d..d+3 (8B aligned)
                    v[dy][0] = b2f(R[-1]);
                    v[dy][1] = b2f((uint16_t)m.x);
                    v[dy][2] = b2f((uint16_t)(m.x >> 16));
                    v[dy][3] = b2f((uint16_t)m.y);
                    v[dy][4] = b2f((uint16_t)(m.y >> 16));
                    v[dy][5] = b2f(R[4]);
                }
                float p0[4] = {0.f,0.f,0.f,0.f};
                float p1[4] = {0.f,0.f,0.f,0.f};
                float p2[4] = {0.f,0.f,0.f,0.f};
#pragma unroll
                for (int dy = 0; dy < 3; ++dy)
#pragma unroll
                    for (int dd = 0; dd < 3; ++dd) {
                        float w0 = wgt[dy * 3 + dd];
                        float w1 = wgt[9 + dy * 3 + dd];
                        float w2 = wgt[18 + dy * 3 + dd];
#pragma unroll
                        for (int d = 0; d < 4; ++d) {
                            float xv = v[dy][d + dd];
                            if (pl <= 5)            p0[d] += w0 * xv;
                            if (pl >= 1 && pl <= 6) p1[d] += w1 * xv;
                            if (pl >= 2)            p2[d] += w2 * xv;
                        }
                    }
#pragma unroll
                for (int d = 0; d < 4; ++d) {
                    if (pl <= 5)            acc[pl][d]     += p0[d];
                    if (pl >= 1 && pl <= 6) acc[pl - 1][d] += p1[d];
                    if (pl >= 2)            acc[pl - 2][d] += p2[d];
                }
            }
#pragma unroll
            for (int oz = 0; oz < 6; ++oz) {
                uint16_t u0 = f2b(acc[oz][0]), u1 = f2b(acc[oz][1]);
                uint16_t u2 = f2b(acc[oz][2]), u3 = f2b(acc[oz][3]);
                uint2 o;
                o.x = (uint32_t)u0 | ((uint32_t)u1 << 16);
                o.y = (uint32_t)u2 | ((uint32_t)u3 << 16);
                *(uint2*)&dst[(size_t)(z0 + oz) * SD2 + y * SD + c4] = o;
#pragma unroll
                for (int d = 0; d < 4; ++d) ssq += acc[oz][d] * acc[oz][d];
            }
        }
    }

    for (int off = 32; off; off >>= 1) ssq += __shfl_down(ssq, off, 64);
    if ((t & 63) == 0) red[t >> 6] = ssq;
    __syncthreads();
    if (t == 0) atomicAdd(&sums[bc], red[0] + red[1] + red[2] + red[3]);
}

// ---- K3: scores S[b][h][i][j] = sum_n q_i k_j  (MFMA, full n coverage) -------
__global__ __launch_bounds__(256) void k_scores(const bf16* __restrict__ qkv2,
                                                float* __restrict__ scores)
{
    int b = blockIdx.z, h = blockIdx.y;
    const bf16* qb = qkv2 + ((size_t)b * C3 + h * 16) * NSP;
    const bf16* kb = qkv2 + ((size_t)b * C3 + 128 + h * 16) * NSP;
    int t = threadIdx.x, w = t >> 6, lane = t & 63;
    int m = lane & 15, q4 = lane >> 4;
    size_t n0 = (size_t)blockIdx.x * 1024 + (size_t)w * 256 + (size_t)q4 * 8;
    const bf16* qp = qb + (size_t)m * NSP + n0;
    const bf16* kp = kb + (size_t)m * NSP + n0;
    f32x4 acc = (f32x4){0.f, 0.f, 0.f, 0.f};
#pragma unroll
    for (int it = 0; it < 8; ++it) {
        bf16x8 a  = *(const bf16x8*)(qp + it * 32);
        bf16x8 bb = *(const bf16x8*)(kp + it * 32);
        acc = __builtin_amdgcn_mfma_f32_16x16x32_bf16(a, bb, acc, 0, 0, 0);
    }
    float* srow = scores + (size_t)(b * NH + h) * 256;
#pragma unroll
    for (int r = 0; r < 4; ++r)
        atomicAdd(&srow[(q4 * 4 + r) * 16 + m], acc[r]);
}

// ---- K4: normalize + temperature + softmax -----------------------------------
__global__ void k_softmax(const float* __restrict__ scores,
                          const float* __restrict__ sums,
                          const bf16* __restrict__ temp,
                          float* __restrict__ attn)
{
    int t = threadIdx.x;             // t = b*128 + h*16 + i
    int h = (t >> 4) & 7, b = t >> 7;
    float tau = __bfloat162float(temp[h]);
    float invq = 1.f / fmaxf(sqrtf(sums[b * C3 + (t & 127)]), 1e-12f);
    const float* srow = scores + (size_t)t * 16;
    float s[16]; float mx = -3.4e38f;
#pragma unroll
    for (int j = 0; j < 16; ++j) {
        float invk = 1.f / fmaxf(sqrtf(sums[b * C3 + 128 + h * 16 + j]), 1e-12f);
        s[j] = srow[j] * invq * invk * tau;
        mx = fmaxf(mx, s[j]);
    }
    float sum = 0.f;
#pragma unroll
    for (int j = 0; j < 16; ++j) { s[j] = expf(s[j] - mx); sum += s[j]; }
    float inv = 1.f / sum;
    float* arow = attn + (size_t)t * 16;
#pragma unroll
    for (int j = 0; j < 16; ++j) arow[j] = s[j] * inv;
}

// ---- K5: outT[b][n][h*16+i] = sum_j attn[i][j] v[j][n] -----------------------
__global__ __launch_bounds__(256) void k_av(const bf16* __restrict__ qkv2,
                                            const float* __restrict__ attn,
                                            bf16* __restrict__ outT)
{
    int b = blockIdx.z, h = blockIdx.y;
    const bf16* vb = qkv2 + ((size_t)b * C3 + 256 + h * 16) * NSP;
    __shared__ float at[256];        // at[j*16+i]
    int t = threadIdx.x;
    {
        int i = t >> 4, j = t & 15;
        at[j * 16 + i] = attn[(size_t)(b * NH + h) * 256 + t];
    }
    __syncthreads();
    size_t n0 = (size_t)blockIdx.x * 1024 + (size_t)t * 4;
    float acc[16][4];
#pragma unroll
    for (int i = 0; i < 16; ++i)
#pragma unroll
        for (int k = 0; k < 4; ++k) acc[i][k] = 0.f;
#pragma unroll
    for (int j = 0; j < 16; ++j) {
        uint2 raw = *(const uint2*)&vb[(size_t)j * NSP + n0];
        const bf16* rp = (const bf16*)&raw;
        float vf[4];
#pragma unroll
        for (int k = 0; k < 4; ++k) vf[k] = ldb(&rp[k]);
#pragma unroll
        for (int i = 0; i < 16; ++i) {
            float wv = at[j * 16 + i];
#pragma unroll
            for (int k = 0; k < 4; ++k) acc[i][k] += wv * vf[k];
        }
    }
    bf16* ob = outT + ((size_t)b * NSP + n0) * CIN + h * 16;
#pragma unroll
    for (int k = 0; k < 4; ++k) {
        bf16 tmp[16];
#pragma unroll
        for (int i = 0; i < 16; ++i) tmp[i] = __float2bfloat16(acc[i][k]);
        *(uint4*)&ob[(size_t)k * CIN]     = *(uint4*)&tmp[0];
        *(uint4*)&ob[(size_t)k * CIN + 8] = *(uint4*)&tmp[8];
    }
}

// ---- host --------------------------------------------------------------------
extern "C" void kernel_launch(void* const* d_in, const int* in_sizes, int n_in,
                              void* d_out, int out_size, void* d_ws, size_t ws_size,
                              hipStream_t stream)
{
    const void *px = nullptr, *pq = nullptr, *pd = nullptr, *pp = nullptr, *pt = nullptr;
    for (int i = 0; i < n_in; ++i) {
        switch (in_sizes[i]) {
            case 28311552: px = d_in[i]; break;   // x
            case 49152:    pq = d_in[i]; break;   // qkv_w
            case 10368:    pd = d_in[i]; break;   // dw_w
            case 16384:    pp = d_in[i]; break;   // proj_w
            case 8:        pt = d_in[i]; break;   // temperature
        }
    }
    const size_t required = NQ * 4 + (1u << 20);
    if (!px || !pq || !pd || !pp || !pt || ws_size < required) {
        (void)hipMemsetAsync(d_out, 0, (size_t)out_size * 2, stream);
        return;
    }

    char* ws = (char*)d_ws;
    bf16* qkv1 = (bf16*)ws;                       // NQ bf16
    bf16* qkv2 = (bf16*)(ws + NQ * 2);            // NQ bf16
    char* small = ws + NQ * 4;
    int*   flag   = (int*)small;
    float* sums   = (float*)(small + 256);
    float* scores = (float*)(small + 8192);
    float* attn   = (float*)(small + 24576);
    bf16*  wbuf   = (bf16*)(small + 40960);
    bf16* outT = qkv1;   // alias: qkv1 dead after k_dwconv

    (void)hipMemsetAsync(small, 0, 40960, stream);  // flag, sums, scores, attn
    k_sniff<<<1, 256, 0, stream>>>((const uint16_t*)px, flag);
    k_cvtw<<<(WTOTAL + 255) / 256, 256, 0, stream>>>(pq, pd, pp, pt, wbuf, flag);
    k_gemm_qkv<<<dim3(864 * 3, 1, NB), 256, 0, stream>>>(
        wbuf + WOFF_QKVW, px, qkv1, flag);
    k_dwconv<<<dim3(NB * C3, 8), 256, 0, stream>>>(qkv1, wbuf + WOFF_DWW, qkv2, sums);
    k_scores<<<dim3(108, NH, NB), 256, 0, stream>>>(qkv2, scores);
    k_softmax<<<1, 256, 0, stream>>>(scores, sums, wbuf + WOFF_TEMP, attn);
    k_av<<<dim3(108, NH, NB), 256, 0, stream>>>(qkv2, attn, outT);
    k_gemm_bt<<<dim3(864, 1, NB), 256, 0, stream>>>(
        wbuf + WOFF_PROJ, outT, d_out, CIN, flag, 1);
}